// Round 14
// baseline (222.974 us; speedup 1.0000x reference)
//
#include <hip/hip_runtime.h>

// Ragged gather-to-padded for SparseConvUnet preprocessing.
// feature: [Nrows, 128] f32 packed; atom_num: [N] int32 in [0,14);
// out = concat( padded [N,14,128] f32 (zero where slot>=atom_num), label as f32 [N] ).
//
// R14: stream-separation experiment. R6's single mixed gather (5.4 TB/s) is
// split into two pure-regime kernels over disjoint output bytes:
//   k_copy: valid rows only  (~333MB read + ~333MB write, 1:1 copy regime)
//   k_zero: invalid tail slots only (~384MB pure write, fill regime)
// Same resident 512x1024 grid / interleaved tiles / nt ops as R6.

#define MAX_ATOMS 14
#define F4_PER_ROW 32                       // 128 floats = 32 float4
#define F4_PER_RES (MAX_ATOMS * F4_PER_ROW) // 448 = 7 * 64
#define TILE 16                             // residues per block-iteration (= waves/block)
#define GBLOCKS 512
#define GTHREADS 1024

typedef float f32x4 __attribute__((ext_vector_type(4)));

// ---- kernel A: per-256-residue chunk sums ----
__global__ __launch_bounds__(256) void k_sums(const int* __restrict__ atom_num,
                                              int n, int* __restrict__ sums) {
    __shared__ int lds[256];
    int t = threadIdx.x;
    int r = blockIdx.x * 256 + t;
    lds[t] = (r < n) ? atom_num[r] : 0;
    __syncthreads();
    for (int d = 128; d > 0; d >>= 1) {
        if (t < d) lds[t] += lds[t + d];
        __syncthreads();
    }
    if (t == 0) sums[blockIdx.x] = lds[0];
}

// ---- kernel B: per-residue offsets + label cast ----
__global__ __launch_bounds__(256) void k_prep(const int* __restrict__ atom_num,
                                              const int* __restrict__ sums,
                                              const int* __restrict__ label,
                                              int n,
                                              int* __restrict__ offsets,
                                              float* __restrict__ out_label) {
    __shared__ int red[256];
    __shared__ int scn[256];
    int t = threadIdx.x;
    int b = blockIdx.x;
    int part = 0;
    for (int j = t; j < b; j += 256) part += sums[j];
    red[t] = part;
    __syncthreads();
    for (int d = 128; d > 0; d >>= 1) {
        if (t < d) red[t] += red[t + d];
        __syncthreads();
    }
    int base = red[0];
    int r = b * 256 + t;
    int v = (r < n) ? atom_num[r] : 0;
    scn[t] = v;
    __syncthreads();
    for (int d = 1; d < 256; d <<= 1) {
        int add = (t >= d) ? scn[t - d] : 0;
        __syncthreads();
        scn[t] += add;
        __syncthreads();
    }
    if (r < n) {
        offsets[r] = base + scn[t] - v;
        out_label[r] = (float)label[r];     // harness reads d_out as f32
    }
}

// ---- kernel C1: copier — valid rows only (1:1 copy regime) ----
__global__ __launch_bounds__(GTHREADS, 8) void k_copy(
        const f32x4* __restrict__ feat,
        const int* __restrict__ atom_num,
        const int* __restrict__ offsets,
        f32x4* __restrict__ out,
        int n, int ntiles) {
    int w       = threadIdx.x >> 6;        // wave 0..15
    int lane    = threadIdx.x & 63;
    int halfrow = lane >> 5;               // which row of the lane's pair

    for (int tile = blockIdx.x; tile < ntiles; tile += GBLOCKS) {
        int r = tile * TILE + w;           // one residue per wave
        if (r < n) {
            int off = offsets[r];          // wave-uniform broadcast load (L2-hot)
            int cnt = atom_num[r];
            const f32x4* fp = feat + (size_t)off * F4_PER_ROW + lane;
            f32x4* op = out + (size_t)r * F4_PER_RES + lane;
            #pragma unroll
            for (int i = 0; i < 7; ++i) {
                if (2 * i + halfrow < cnt) {   // exec-masked; empty iters skip
                    f32x4 v = __builtin_nontemporal_load(fp + i * 64);
                    __builtin_nontemporal_store(v, op + i * 64);
                }
            }
        }
    }
}

// ---- kernel C2: zeroer — invalid tail slots only (fill regime) ----
__global__ __launch_bounds__(GTHREADS, 8) void k_zero(
        const int* __restrict__ atom_num,
        f32x4* __restrict__ out,
        int n, int ntiles) {
    int w       = threadIdx.x >> 6;
    int lane    = threadIdx.x & 63;
    int halfrow = lane >> 5;
    const f32x4 z = (f32x4)0.f;

    for (int tile = blockIdx.x; tile < ntiles; tile += GBLOCKS) {
        int r = tile * TILE + w;
        if (r < n) {
            int cnt = atom_num[r];         // L2-hot broadcast
            f32x4* op = out + (size_t)r * F4_PER_RES + lane;
            #pragma unroll
            for (int i = 0; i < 7; ++i) {
                if (2 * i + halfrow >= cnt)
                    __builtin_nontemporal_store(z, op + i * 64);
            }
        }
    }
}

extern "C" void kernel_launch(void* const* d_in, const int* in_sizes, int n_in,
                              void* d_out, int out_size, void* d_ws, size_t ws_size,
                              hipStream_t stream) {
    const float* feature = (const float*)d_in[0];
    const int* atom_num  = (const int*)d_in[1];
    const int* label     = (const int*)d_in[2];
    const int n = in_sizes[1];               // N_res = 100000

    float* out = (float*)d_out;
    float* out_label = out + (size_t)n * MAX_ATOMS * 128;

    int nb = (n + 255) / 256;                // 391
    int* ws_sums    = (int*)d_ws;            // nb ints
    int* ws_offsets = ws_sums + nb;          // n ints

    k_sums<<<nb, 256, 0, stream>>>(atom_num, n, ws_sums);
    k_prep<<<nb, 256, 0, stream>>>(atom_num, ws_sums, label, n,
                                   ws_offsets, out_label);

    int ntiles = (n + TILE - 1) / TILE;      // 6250
    k_copy<<<GBLOCKS, GTHREADS, 0, stream>>>(
        (const f32x4*)feature, atom_num, ws_offsets,
        (f32x4*)out, n, ntiles);
    k_zero<<<GBLOCKS, GTHREADS, 0, stream>>>(
        atom_num, (f32x4*)out, n, ntiles);
}

// Round 15
// 206.962 us; speedup vs baseline: 1.0774x; 1.0774x over previous
//
#include <hip/hip_runtime.h>

// Ragged gather-to-padded for SparseConvUnet preprocessing.
// feature: [Nrows, 128] f32 packed; atom_num: [N] int32 in [0,14);
// out = concat( padded [N,14,128] f32 (zero where slot>=atom_num), label as f32 [N] ).
//
// FINAL (= R6/R13, best measured config, 206.8us reproduced twice):
//  - k_sums + k_prep (391 blocks each): per-256-chunk totals, then per-residue
//    offsets from L2-hot chunk sums + label cast.
//  - k_gather: 512x1024 (exactly resident, 2 blocks/CU), stride-interleaved
//    16-residue tiles (compact ~58MB rolling front, 512 lockstep streams),
//    nt loads + nt stores, per-lane-masked loads (scheduler-friendly).
// Closed axes (14 experiments): issue shape, cache hints (nt+nt best),
// concurrency (512 streams best), partition (compact interleave best),
// burst shaping (regressed), launch fusion (3-launch best), stream
// separation (regressed). Mixed-stream rate ~5.4 TB/s = measured plateau.

#define MAX_ATOMS 14
#define F4_PER_ROW 32                       // 128 floats = 32 float4
#define F4_PER_RES (MAX_ATOMS * F4_PER_ROW) // 448 = 7 * 64
#define TILE 16                             // residues per block-iteration (= waves/block)
#define GBLOCKS 512
#define GTHREADS 1024

typedef float f32x4 __attribute__((ext_vector_type(4)));

// ---- kernel A: per-256-residue chunk sums ----
__global__ __launch_bounds__(256) void k_sums(const int* __restrict__ atom_num,
                                              int n, int* __restrict__ sums) {
    __shared__ int lds[256];
    int t = threadIdx.x;
    int r = blockIdx.x * 256 + t;
    lds[t] = (r < n) ? atom_num[r] : 0;
    __syncthreads();
    for (int d = 128; d > 0; d >>= 1) {
        if (t < d) lds[t] += lds[t + d];
        __syncthreads();
    }
    if (t == 0) sums[blockIdx.x] = lds[0];
}

// ---- kernel B: per-residue offsets + label cast ----
__global__ __launch_bounds__(256) void k_prep(const int* __restrict__ atom_num,
                                              const int* __restrict__ sums,
                                              const int* __restrict__ label,
                                              int n,
                                              int* __restrict__ offsets,
                                              float* __restrict__ out_label) {
    __shared__ int red[256];
    __shared__ int scn[256];
    int t = threadIdx.x;
    int b = blockIdx.x;
    int part = 0;
    for (int j = t; j < b; j += 256) part += sums[j];
    red[t] = part;
    __syncthreads();
    for (int d = 128; d > 0; d >>= 1) {
        if (t < d) red[t] += red[t + d];
        __syncthreads();
    }
    int base = red[0];
    int r = b * 256 + t;
    int v = (r < n) ? atom_num[r] : 0;
    scn[t] = v;
    __syncthreads();
    for (int d = 1; d < 256; d <<= 1) {
        int add = (t >= d) ? scn[t - d] : 0;
        __syncthreads();
        scn[t] += add;
        __syncthreads();
    }
    if (r < n) {
        offsets[r] = base + scn[t] - v;
        out_label[r] = (float)label[r];     // harness reads d_out as f32
    }
}

// ---- kernel C: pure streaming gather, fully resident, lockstep front ----
__global__ __launch_bounds__(GTHREADS, 8) void k_gather(
        const f32x4* __restrict__ feat,
        const int* __restrict__ atom_num,
        const int* __restrict__ offsets,
        f32x4* __restrict__ out,
        int n, int ntiles) {
    int w       = threadIdx.x >> 6;        // wave 0..15
    int lane    = threadIdx.x & 63;
    int halfrow = lane >> 5;               // which row of the lane's pair

    for (int tile = blockIdx.x; tile < ntiles; tile += GBLOCKS) {
        int r = tile * TILE + w;           // one residue per wave
        if (r < n) {
            int off = offsets[r];          // wave-uniform broadcast load (L2-hot)
            int cnt = atom_num[r];
            const f32x4* fp = feat + (size_t)off * F4_PER_ROW + lane;
            f32x4* op = out + (size_t)r * F4_PER_RES + lane;
            #pragma unroll
            for (int i = 0; i < 7; ++i) {
                f32x4 v = (f32x4)0.f;
                if (2 * i + halfrow < cnt)
                    v = __builtin_nontemporal_load(fp + i * 64);
                __builtin_nontemporal_store(v, op + i * 64);
            }
        }
    }
}

extern "C" void kernel_launch(void* const* d_in, const int* in_sizes, int n_in,
                              void* d_out, int out_size, void* d_ws, size_t ws_size,
                              hipStream_t stream) {
    const float* feature = (const float*)d_in[0];
    const int* atom_num  = (const int*)d_in[1];
    const int* label     = (const int*)d_in[2];
    const int n = in_sizes[1];               // N_res = 100000

    float* out = (float*)d_out;
    float* out_label = out + (size_t)n * MAX_ATOMS * 128;

    int nb = (n + 255) / 256;                // 391
    int* ws_sums    = (int*)d_ws;            // nb ints
    int* ws_offsets = ws_sums + nb;          // n ints

    k_sums<<<nb, 256, 0, stream>>>(atom_num, n, ws_sums);
    k_prep<<<nb, 256, 0, stream>>>(atom_num, ws_sums, label, n,
                                   ws_offsets, out_label);

    int ntiles = (n + TILE - 1) / TILE;      // 6250
    k_gather<<<GBLOCKS, GTHREADS, 0, stream>>>(
        (const f32x4*)feature, atom_num, ws_offsets,
        (f32x4*)out, n, ntiles);
}